// Round 1
// baseline (892.095 us; speedup 1.0000x reference)
//
#include <hip/hip_runtime.h>
#include <math.h>

// Problem constants (fixed by setup_inputs)
constexpr int B_ = 2, T_ = 2048, C_ = 512, H_ = 8, D_ = 64;
constexpr int QKVG_ = 3 * H_ * D_ + H_;   // 1544
constexpr float GATE_BIAS_ = 6.906768f;

// ---------------------------------------------------------------------------
// GEMM fp32: C[M,N] = A[M,K] @ B[K,N]   (row-major, M%128==0, K%16==0)
// tile 128x64, 256 threads, 8x4 micro-tile per thread
// ---------------------------------------------------------------------------
__global__ __launch_bounds__(256) void gemm_f32(
    const float* __restrict__ A, const float* __restrict__ Bm,
    float* __restrict__ C, int M, int N, int K)
{
    __shared__ float As[16][132];   // [k][m], padded (row=528B, 16B-aligned)
    __shared__ float Bs[16][68];    // [k][n], padded (row=272B, 16B-aligned)

    const int tid = threadIdx.x;
    const int tx = tid & 15;        // col group (4 cols)
    const int ty = tid >> 4;        // row group (8 rows)
    const int m0 = blockIdx.y * 128;
    const int n0 = blockIdx.x * 64;

    float acc[8][4];
#pragma unroll
    for (int i = 0; i < 8; ++i)
#pragma unroll
        for (int j = 0; j < 4; ++j) acc[i][j] = 0.f;

    const int am = tid >> 1;          // 0..127
    const int ak = (tid & 1) * 8;     // 0 or 8
    const int bk = tid >> 4;          // 0..15
    const int bn = (tid & 15) * 4;    // 0..60

    for (int k0 = 0; k0 < K; k0 += 16) {
        // ---- stage A tile (transposed to [k][m]) ----
        const float* ap = A + (size_t)(m0 + am) * K + k0 + ak;
        float4 a0 = *(const float4*)(ap);
        float4 a1 = *(const float4*)(ap + 4);
        As[ak + 0][am] = a0.x; As[ak + 1][am] = a0.y;
        As[ak + 2][am] = a0.z; As[ak + 3][am] = a0.w;
        As[ak + 4][am] = a1.x; As[ak + 5][am] = a1.y;
        As[ak + 6][am] = a1.z; As[ak + 7][am] = a1.w;
        // ---- stage B tile ----
        {
            const int gn = n0 + bn;
            float4 bv = make_float4(0.f, 0.f, 0.f, 0.f);
            const float* bp = Bm + (size_t)(k0 + bk) * N + gn;
            if (gn + 3 < N) {
                bv = *(const float4*)bp;
            } else if (gn < N) {
                bv.x = bp[0];
                if (gn + 1 < N) bv.y = bp[1];
                if (gn + 2 < N) bv.z = bp[2];
            }
            *(float4*)&Bs[bk][bn] = bv;
        }
        __syncthreads();
#pragma unroll
        for (int kk = 0; kk < 16; ++kk) {
            float4 x0 = *(const float4*)&As[kk][ty * 8];
            float4 x1 = *(const float4*)&As[kk][ty * 8 + 4];
            float4 bb = *(const float4*)&Bs[kk][tx * 4];
            const float av[8] = {x0.x, x0.y, x0.z, x0.w, x1.x, x1.y, x1.z, x1.w};
            const float bw[4] = {bb.x, bb.y, bb.z, bb.w};
#pragma unroll
            for (int i = 0; i < 8; ++i)
#pragma unroll
                for (int j = 0; j < 4; ++j)
                    acc[i][j] += av[i] * bw[j];
        }
        __syncthreads();
    }

#pragma unroll
    for (int i = 0; i < 8; ++i) {
        const int row = m0 + ty * 8 + i;
#pragma unroll
        for (int j = 0; j < 4; ++j) {
            const int col = n0 + tx * 4 + j;
            if (col < N) C[(size_t)row * N + col] = acc[i][j];
        }
    }
}

// ---------------------------------------------------------------------------
// prep: RoPE q,k in-place + log-sigmoid gate -> Lg[(b*H+h)*T + t]
// one thread per (b,t,h,pair i); gid bits: i:5 | h:3 | t:11 | b:1
// ---------------------------------------------------------------------------
__global__ __launch_bounds__(256) void prep_kernel(
    float* __restrict__ qkvg, float* __restrict__ Lg)
{
    const int gid = blockIdx.x * 256 + threadIdx.x;   // 2^20 threads exactly
    const int i = gid & 31;
    const int h = (gid >> 5) & 7;
    const int t = (gid >> 8) & 2047;
    const int b = gid >> 19;

    // div_i = 2*pi / T^(i/32); T=2048 => exact in double, cast to f32
    const float div = (float)(6.283185307179586 / pow(2048.0, (double)i * (1.0 / 32.0)));
    const float ang = (float)t * div;
    const float sn = sinf(ang);
    const float cs = cosf(ang);

    float* qp = qkvg + (size_t)(b * T_ + t) * QKVG_ + h * 64 + 2 * i;
    float x1 = qp[0], x2 = qp[1];
    qp[0] = x1 * cs - x2 * sn;
    qp[1] = x2 * cs + x1 * sn;
    float* kp = qp + 512;
    x1 = kp[0]; x2 = kp[1];
    kp[0] = x1 * cs - x2 * sn;
    kp[1] = x2 * cs + x1 * sn;

    if (i == 0) {
        const float z = qkvg[(size_t)(b * T_ + t) * QKVG_ + 1536 + h] + GATE_BIAS_;
        // stable log_sigmoid
        const float lg = (z > 0.f) ? -log1pf(expf(-z)) : (z - log1pf(expf(z)));
        Lg[(size_t)(b * H_ + h) * T_ + t] = lg;
    }
}

// ---------------------------------------------------------------------------
// cumsum over t for each (b,h): one wave (64 lanes) per row, shfl prefix scan
// ---------------------------------------------------------------------------
__global__ __launch_bounds__(64) void cumsum_kernel(float* __restrict__ Lg)
{
    const int bh = blockIdx.x;
    const int lane = threadIdx.x;
    float* p = Lg + (size_t)bh * T_;
    float carry = 0.f;
    for (int c0 = 0; c0 < T_; c0 += 64) {
        float v = p[c0 + lane];
#pragma unroll
        for (int off = 1; off < 64; off <<= 1) {
            float n = __shfl_up(v, off, 64);
            if (lane >= off) v += n;
        }
        v += carry;
        p[c0 + lane] = v;
        carry = __shfl(v, 63, 64);
    }
}

// ---------------------------------------------------------------------------
// attention: per block = 64 t-rows of one (b,h); K/V 64x64 tiles in LDS
// 256 threads: 4 lanes per row (16 dims each), shfl_xor dot reduce
// scores p = (q.k/8)^2 * exp(L_t - L_s), causal; y = sum(p v)/max(sum p,1e-6)
// ---------------------------------------------------------------------------
__global__ __launch_bounds__(256) void attn_kernel(
    const float* __restrict__ qkvg, const float* __restrict__ L,
    float* __restrict__ yb)
{
    __shared__ float Ks[64][64];
    __shared__ float Vs[64][64];
    __shared__ float Ls[64];

    const int tid = threadIdx.x;
    const int r = tid >> 2;      // local t-row 0..63
    const int c = tid & 3;       // dim group (16 floats)
    const int bt = blockIdx.x;   // t tile
    const int bh = blockIdx.y;
    const int b = bh >> 3, h = bh & 7;
    const int t = bt * 64 + r;

    const float* qrow = qkvg + (size_t)(b * T_ + t) * QKVG_ + h * 64 + c * 16;
    const float4 q0 = *(const float4*)(qrow + 0);
    const float4 q1 = *(const float4*)(qrow + 4);
    const float4 q2 = *(const float4*)(qrow + 8);
    const float4 q3 = *(const float4*)(qrow + 12);
    const float Lt = L[(size_t)bh * T_ + t];

    float4 y0 = {0,0,0,0}, y1 = {0,0,0,0}, y2 = {0,0,0,0}, y3 = {0,0,0,0};
    float den = 0.f;

    for (int st = 0; st <= bt; ++st) {
        // stage K,V tiles (each thread: 16+16 floats of row r)
        const float* kp = qkvg + (size_t)(b * T_ + st * 64 + r) * QKVG_ + 512 + h * 64 + c * 16;
        *(float4*)&Ks[r][c * 16 +  0] = *(const float4*)(kp + 0);
        *(float4*)&Ks[r][c * 16 +  4] = *(const float4*)(kp + 4);
        *(float4*)&Ks[r][c * 16 +  8] = *(const float4*)(kp + 8);
        *(float4*)&Ks[r][c * 16 + 12] = *(const float4*)(kp + 12);
        const float* vp = kp + 512;
        *(float4*)&Vs[r][c * 16 +  0] = *(const float4*)(vp + 0);
        *(float4*)&Vs[r][c * 16 +  4] = *(const float4*)(vp + 4);
        *(float4*)&Vs[r][c * 16 +  8] = *(const float4*)(vp + 8);
        *(float4*)&Vs[r][c * 16 + 12] = *(const float4*)(vp + 12);
        if (tid < 64) Ls[tid] = L[(size_t)bh * T_ + st * 64 + tid];
        __syncthreads();

        const int smax = (st == bt) ? r : 63;
#pragma unroll 4
        for (int s = 0; s < 64; ++s) {
            const float4* kr = (const float4*)&Ks[s][c * 16];
            const float4 k0 = kr[0], k1 = kr[1], k2 = kr[2], k3 = kr[3];
            float d = q0.x * k0.x + q0.y * k0.y + q0.z * k0.z + q0.w * k0.w;
            d += q1.x * k1.x + q1.y * k1.y + q1.z * k1.z + q1.w * k1.w;
            d += q2.x * k2.x + q2.y * k2.y + q2.z * k2.z + q2.w * k2.w;
            d += q3.x * k3.x + q3.y * k3.y + q3.z * k3.z + q3.w * k3.w;
            d += __shfl_xor(d, 1, 64);
            d += __shfl_xor(d, 2, 64);          // all 4 lanes now hold full dot
            const float qk = d * 0.125f;        // 1/sqrt(64)
            float p = qk * qk * __expf(Lt - Ls[s]);
            p = (s <= smax) ? p : 0.f;
            den += p;
            const float4* vr = (const float4*)&Vs[s][c * 16];
            const float4 v0 = vr[0], v1 = vr[1], v2 = vr[2], v3 = vr[3];
            y0.x += p * v0.x; y0.y += p * v0.y; y0.z += p * v0.z; y0.w += p * v0.w;
            y1.x += p * v1.x; y1.y += p * v1.y; y1.z += p * v1.z; y1.w += p * v1.w;
            y2.x += p * v2.x; y2.y += p * v2.y; y2.z += p * v2.z; y2.w += p * v2.w;
            y3.x += p * v3.x; y3.y += p * v3.y; y3.z += p * v3.z; y3.w += p * v3.w;
        }
        __syncthreads();
    }

    const float inv = 1.0f / fmaxf(den, 1e-6f);
    float* yo = yb + (size_t)(b * T_ + t) * (H_ * D_) + h * 64 + c * 16;
    y0.x *= inv; y0.y *= inv; y0.z *= inv; y0.w *= inv;
    y1.x *= inv; y1.y *= inv; y1.z *= inv; y1.w *= inv;
    y2.x *= inv; y2.y *= inv; y2.z *= inv; y2.w *= inv;
    y3.x *= inv; y3.y *= inv; y3.z *= inv; y3.w *= inv;
    *(float4*)(yo + 0)  = y0;
    *(float4*)(yo + 4)  = y1;
    *(float4*)(yo + 8)  = y2;
    *(float4*)(yo + 12) = y3;
}

// ---------------------------------------------------------------------------
extern "C" void kernel_launch(void* const* d_in, const int* in_sizes, int n_in,
                              void* d_out, int out_size, void* d_ws, size_t ws_size,
                              hipStream_t stream)
{
    const float* x      = (const float*)d_in[0];
    const float* w_attn = (const float*)d_in[1];
    const float* w_proj = (const float*)d_in[2];
    float* out = (float*)d_out;

    // workspace layout (floats): qkvg | Lg | yb  -> 33.8 MB total
    float* qkvg = (float*)d_ws;
    float* Lg   = qkvg + (size_t)B_ * T_ * QKVG_;   // 6,322,176 floats
    float* yb   = Lg + (size_t)B_ * H_ * T_;        // +32,768 floats

    const int M = B_ * T_;   // 4096

    // 1) qkvg = x @ w_attn   (4096 x 1544 x 512)
    gemm_f32<<<dim3((QKVG_ + 63) / 64, M / 128), 256, 0, stream>>>(
        x, w_attn, qkvg, M, QKVG_, C_);

    // 2) RoPE(q,k) in-place + log-sigmoid gate
    prep_kernel<<<(B_ * T_ * H_ * 32) / 256, 256, 0, stream>>>(qkvg, Lg);

    // 3) cumsum over t per (b,h)
    cumsum_kernel<<<B_ * H_, 64, 0, stream>>>(Lg);

    // 4) gated sympow attention -> yb (4096 x 512)
    attn_kernel<<<dim3(T_ / 64, B_ * H_), 256, 0, stream>>>(qkvg, Lg, yb);

    // 5) out = yb @ w_proj   (4096 x 512 x 512)
    gemm_f32<<<dim3(C_ / 64, M / 128), 256, 0, stream>>>(
        yb, w_proj, out, M, C_, H_ * D_);
}

// Round 3
// 250.951 us; speedup vs baseline: 3.5549x; 3.5549x over previous
//
#include <hip/hip_runtime.h>
#include <math.h>

// Problem constants (fixed by setup_inputs)
constexpr int B_ = 2, T_ = 2048, C_ = 512, H_ = 8, D_ = 64;
constexpr int QKVG_ = 3 * H_ * D_ + H_;   // 1544
constexpr float GATE_BIAS_ = 6.906768f;

typedef __attribute__((ext_vector_type(8))) short short8;
typedef __attribute__((ext_vector_type(4))) float f32x4;

__device__ __forceinline__ unsigned short f2b(float f) {
    unsigned int u = __float_as_uint(f);
    unsigned int r = (u + 0x7fffu + ((u >> 16) & 1u)) >> 16;   // RNE
    return (unsigned short)r;
}
__device__ __forceinline__ short8 pack8(float4 a, float4 b) {
    short8 r;
    r[0] = (short)f2b(a.x); r[1] = (short)f2b(a.y);
    r[2] = (short)f2b(a.z); r[3] = (short)f2b(a.w);
    r[4] = (short)f2b(b.x); r[5] = (short)f2b(b.y);
    r[6] = (short)f2b(b.z); r[7] = (short)f2b(b.w);
    return r;
}

// ---------------------------------------------------------------------------
// GEMM fp32 (unchanged): C[M,N] = A[M,K] @ B[K,N]; tile 128x64
// ---------------------------------------------------------------------------
__global__ __launch_bounds__(256) void gemm_f32(
    const float* __restrict__ A, const float* __restrict__ Bm,
    float* __restrict__ C, int M, int N, int K)
{
    __shared__ float As[16][132];
    __shared__ float Bs[16][68];

    const int tid = threadIdx.x;
    const int tx = tid & 15;
    const int ty = tid >> 4;
    const int m0 = blockIdx.y * 128;
    const int n0 = blockIdx.x * 64;

    float acc[8][4];
#pragma unroll
    for (int i = 0; i < 8; ++i)
#pragma unroll
        for (int j = 0; j < 4; ++j) acc[i][j] = 0.f;

    const int am = tid >> 1;
    const int ak = (tid & 1) * 8;
    const int bk = tid >> 4;
    const int bn = (tid & 15) * 4;

    for (int k0 = 0; k0 < K; k0 += 16) {
        const float* ap = A + (size_t)(m0 + am) * K + k0 + ak;
        float4 a0 = *(const float4*)(ap);
        float4 a1 = *(const float4*)(ap + 4);
        As[ak + 0][am] = a0.x; As[ak + 1][am] = a0.y;
        As[ak + 2][am] = a0.z; As[ak + 3][am] = a0.w;
        As[ak + 4][am] = a1.x; As[ak + 5][am] = a1.y;
        As[ak + 6][am] = a1.z; As[ak + 7][am] = a1.w;
        {
            const int gn = n0 + bn;
            float4 bv = make_float4(0.f, 0.f, 0.f, 0.f);
            const float* bp = Bm + (size_t)(k0 + bk) * N + gn;
            if (gn + 3 < N) {
                bv = *(const float4*)bp;
            } else if (gn < N) {
                bv.x = bp[0];
                if (gn + 1 < N) bv.y = bp[1];
                if (gn + 2 < N) bv.z = bp[2];
            }
            *(float4*)&Bs[bk][bn] = bv;
        }
        __syncthreads();
#pragma unroll
        for (int kk = 0; kk < 16; ++kk) {
            float4 x0 = *(const float4*)&As[kk][ty * 8];
            float4 x1 = *(const float4*)&As[kk][ty * 8 + 4];
            float4 bb = *(const float4*)&Bs[kk][tx * 4];
            const float av[8] = {x0.x, x0.y, x0.z, x0.w, x1.x, x1.y, x1.z, x1.w};
            const float bw[4] = {bb.x, bb.y, bb.z, bb.w};
#pragma unroll
            for (int i = 0; i < 8; ++i)
#pragma unroll
                for (int j = 0; j < 4; ++j)
                    acc[i][j] += av[i] * bw[j];
        }
        __syncthreads();
    }

#pragma unroll
    for (int i = 0; i < 8; ++i) {
        const int row = m0 + ty * 8 + i;
#pragma unroll
        for (int j = 0; j < 4; ++j) {
            const int col = n0 + tx * 4 + j;
            if (col < N) C[(size_t)row * N + col] = acc[i][j];
        }
    }
}

// ---------------------------------------------------------------------------
// prep: RoPE q,k in-place + log-sigmoid gate -> Lg
// ---------------------------------------------------------------------------
__global__ __launch_bounds__(256) void prep_kernel(
    float* __restrict__ qkvg, float* __restrict__ Lg)
{
    const int gid = blockIdx.x * 256 + threadIdx.x;
    const int i = gid & 31;
    const int h = (gid >> 5) & 7;
    const int t = (gid >> 8) & 2047;
    const int b = gid >> 19;

    const float div = 6.2831853071795864f * exp2f((float)i * (-11.0f / 32.0f));
    const float ang = (float)t * div;
    const float sn = sinf(ang);
    const float cs = cosf(ang);

    float* qp = qkvg + (size_t)(b * T_ + t) * QKVG_ + h * 64 + 2 * i;
    float x1 = qp[0], x2 = qp[1];
    qp[0] = x1 * cs - x2 * sn;
    qp[1] = x2 * cs + x1 * sn;
    float* kp = qp + 512;
    x1 = kp[0]; x2 = kp[1];
    kp[0] = x1 * cs - x2 * sn;
    kp[1] = x2 * cs + x1 * sn;

    if (i == 0) {
        const float z = qkvg[(size_t)(b * T_ + t) * QKVG_ + 1536 + h] + GATE_BIAS_;
        const float lg = (z > 0.f) ? -log1pf(expf(-z)) : (z - log1pf(expf(z)));
        Lg[(size_t)(b * H_ + h) * T_ + t] = lg;
    }
}

// ---------------------------------------------------------------------------
// cumsum over t per (b,h) (unchanged)
// ---------------------------------------------------------------------------
__global__ __launch_bounds__(64) void cumsum_kernel(float* __restrict__ Lg)
{
    const int bh = blockIdx.x;
    const int lane = threadIdx.x;
    float* p = Lg + (size_t)bh * T_;
    float carry = 0.f;
    for (int c0 = 0; c0 < T_; c0 += 64) {
        float v = p[c0 + lane];
#pragma unroll
        for (int off = 1; off < 64; off <<= 1) {
            float n = __shfl_up(v, off, 64);
            if (lane >= off) v += n;
        }
        v += carry;
        p[c0 + lane] = v;
        carry = __shfl(v, 63, 64);
    }
}

// ---------------------------------------------------------------------------
// vt_pack: V (fp32, strided inside qkvg) -> Vtb[bh][d][t] bf16 (transposed)
// ---------------------------------------------------------------------------
__global__ __launch_bounds__(256) void vt_pack(
    const float* __restrict__ qkvg, unsigned short* __restrict__ Vtb)
{
    __shared__ float Vs[64][68];
    const int tid = threadIdx.x;
    const int stile = blockIdx.x;
    const int bh = blockIdx.y;
    const int b = bh >> 3, h = bh & 7;

    {
        const int r = tid >> 2, c = tid & 3;
        const float* vp = qkvg + (size_t)(b * T_ + stile * 64 + r) * QKVG_ + 1024 + h * 64 + c * 16;
        *(float4*)&Vs[r][c * 16 + 0]  = *(const float4*)(vp + 0);
        *(float4*)&Vs[r][c * 16 + 4]  = *(const float4*)(vp + 4);
        *(float4*)&Vs[r][c * 16 + 8]  = *(const float4*)(vp + 8);
        *(float4*)&Vs[r][c * 16 + 12] = *(const float4*)(vp + 12);
    }
    __syncthreads();
    {
        const int d = tid >> 2, cc = tid & 3;
        short8 o0, o1;
#pragma unroll
        for (int j = 0; j < 8; ++j) o0[j] = (short)f2b(Vs[cc * 16 + j][d]);
#pragma unroll
        for (int j = 0; j < 8; ++j) o1[j] = (short)f2b(Vs[cc * 16 + 8 + j][d]);
        unsigned short* op = Vtb + (size_t)(bh * 64 + d) * T_ + stile * 64 + cc * 16;
        *(short8*)(op + 0) = o0;
        *(short8*)(op + 8) = o1;
    }
}

// ---------------------------------------------------------------------------
// attn_mfma: 4 waves/block, wave w owns q-rows [t0+16w, t0+16w+16)
// per 64-wide KV tile: QK^T (8 mfma) -> gate/square -> P to LDS (bf16,
// XOR-swizzled) -> PV (8 mfma). den = plain row-sum (scores >= 0).
// swizzle: byte_in_row ^= (row&7)<<4  (rows are 128B)
// ---------------------------------------------------------------------------
__global__ __launch_bounds__(256) void attn_mfma(
    const float* __restrict__ qkvg, const float* __restrict__ L,
    const unsigned short* __restrict__ Vtb, float* __restrict__ yb)
{
    __shared__ __align__(16) char smem[32768];
    char* KsB = smem;                 // 8 KB  [s][d] bf16 swizzled
    char* VtB = smem + 8192;          // 8 KB  [d][s] bf16 swizzled
    char* PsB = smem + 16384;         // 8 KB  4 waves x [16][64] bf16 swizzled
    float* Lall = (float*)(smem + 24576);  // up to 2048 floats

    const int tid = threadIdx.x;
    const int wave = tid >> 6;
    const int lane = tid & 63;
    const int l15 = lane & 15;
    const int lhi = lane >> 4;        // 0..3
    const int bt = blockIdx.x;
    const int bh = blockIdx.y;
    const int b = bh >> 3, h = bh & 7;
    const int t0 = bt * 64;

    // stage cumulative log-gate values [0, (bt+1)*64)
    const float* Lrow = L + (size_t)bh * T_;
    for (int i = tid; i < (bt + 1) * 64; i += 256) Lall[i] = Lrow[i];

    // Q fragments (A-frag: row = l15, k = kk*32 + lhi*8 + j)
    const int qrow = t0 + wave * 16 + l15;
    const float* qp = qkvg + (size_t)(b * T_ + qrow) * QKVG_ + h * 64 + lhi * 8;
    short8 qf[2];
#pragma unroll
    for (int kk = 0; kk < 2; ++kk) {
        float4 f0 = *(const float4*)(qp + kk * 32);
        float4 f1 = *(const float4*)(qp + kk * 32 + 4);
        qf[kk] = pack8(f0, f1);
    }

    __syncthreads();   // Lall visible

    // exp(L_t)/64 for this lane's 4 C-frag rows (row = lhi*4 + r)
    float eLt[4];
#pragma unroll
    for (int r = 0; r < 4; ++r)
        eLt[r] = __expf(Lall[t0 + wave * 16 + lhi * 4 + r]) * (1.0f / 64.0f);

    f32x4 accY[4];
#pragma unroll
    for (int n = 0; n < 4; ++n) accY[n] = (f32x4){0.f, 0.f, 0.f, 0.f};
    float den[4] = {0.f, 0.f, 0.f, 0.f};

    const int kchunk = lhi * 16;      // byte offset of this lane's 16B in a k-half

    for (int st = 0; st <= bt; ++st) {
        __syncthreads();
        // ---- stage K tile (fp32 -> bf16, swizzled) ----
        {
            const int s = tid >> 2, cq = tid & 3;
            const float* kp = qkvg + (size_t)(b * T_ + st * 64 + s) * QKVG_ + 512 + h * 64 + cq * 16;
            float4 k0 = *(const float4*)(kp + 0);
            float4 k1 = *(const float4*)(kp + 4);
            float4 k2 = *(const float4*)(kp + 8);
            float4 k3 = *(const float4*)(kp + 12);
            const int sw = (s & 7) << 4;
            *(short8*)(KsB + s * 128 + ((cq * 32) ^ sw))      = pack8(k0, k1);
            *(short8*)(KsB + s * 128 + ((cq * 32 + 16) ^ sw)) = pack8(k2, k3);
            // ---- stage V^T tile from packed global (bf16, swizzled) ----
            const int d = s;
            const unsigned short* vp = Vtb + (size_t)(bh * 64 + d) * T_ + st * 64 + cq * 16;
            short8 v0 = *(const short8*)(vp + 0);
            short8 v1 = *(const short8*)(vp + 8);
            *(short8*)(VtB + d * 128 + ((cq * 32) ^ sw))      = v0;
            *(short8*)(VtB + d * 128 + ((cq * 32 + 16) ^ sw)) = v1;
        }
        __syncthreads();

        // ---- QK^T: 4 col-tiles x 2 k-halves ----
        f32x4 accS[4];
#pragma unroll
        for (int n = 0; n < 4; ++n) accS[n] = (f32x4){0.f, 0.f, 0.f, 0.f};
        const int rsw = (l15 & 7) << 4;
#pragma unroll
        for (int n = 0; n < 4; ++n) {
#pragma unroll
            for (int kk = 0; kk < 2; ++kk) {
                short8 bf = *(const short8*)(KsB + (n * 16 + l15) * 128 + ((kk * 64 + kchunk) ^ rsw));
                accS[n] = __builtin_amdgcn_mfma_f32_16x16x32_bf16(qf[kk], bf, accS[n], 0, 0, 0);
            }
        }

        // ---- gate + square + causal mask; write P (bf16) to LDS ----
        float eLsi[4];
#pragma unroll
        for (int n = 0; n < 4; ++n)
            eLsi[n] = __expf(-Lall[st * 64 + n * 16 + l15]);
        const bool last = (st == bt);
        char* PsW = PsB + wave * 2048;
#pragma unroll
        for (int n = 0; n < 4; ++n) {
#pragma unroll
            for (int r = 0; r < 4; ++r) {
                const float a = accS[n][r];
                float p = a * a * eLt[r] * eLsi[n];
                if (last) {
                    const int scol = n * 16 + l15;
                    const int trow = lhi * 4 + r;
                    p = (scol <= wave * 16 + trow) ? p : 0.f;
                }
                den[r] += p;
                const int prow = lhi * 4 + r;
                const int pcol = n * 16 + l15;
                *(unsigned short*)(PsW + prow * 128 + ((2 * pcol) ^ ((prow & 7) << 4))) = f2b(p);
            }
        }

        // ---- PV: Y += P @ V ----
        short8 pa[2];
#pragma unroll
        for (int kk = 0; kk < 2; ++kk)
            pa[kk] = *(const short8*)(PsW + l15 * 128 + ((kk * 64 + kchunk) ^ rsw));
#pragma unroll
        for (int n = 0; n < 4; ++n) {
#pragma unroll
            for (int kk = 0; kk < 2; ++kk) {
                short8 vb = *(const short8*)(VtB + (n * 16 + l15) * 128 + ((kk * 64 + kchunk) ^ rsw));
                accY[n] = __builtin_amdgcn_mfma_f32_16x16x32_bf16(pa[kk], vb, accY[n], 0, 0, 0);
            }
        }
    }

    // ---- reduce den across the 16 col-lanes (row sums) ----
#pragma unroll
    for (int r = 0; r < 4; ++r) {
        den[r] += __shfl_xor(den[r], 1, 64);
        den[r] += __shfl_xor(den[r], 2, 64);
        den[r] += __shfl_xor(den[r], 4, 64);
        den[r] += __shfl_xor(den[r], 8, 64);
    }
    float inv[4];
#pragma unroll
    for (int r = 0; r < 4; ++r) inv[r] = 1.0f / fmaxf(den[r], 1e-6f);

    // ---- store Y (fp32): row = t0+16w+lhi*4+r, col = h*64 + n*16 + l15 ----
#pragma unroll
    for (int r = 0; r < 4; ++r) {
        const int t = t0 + wave * 16 + lhi * 4 + r;
        float* yo = yb + (size_t)(b * T_ + t) * (H_ * D_) + h * 64 + l15;
#pragma unroll
        for (int n = 0; n < 4; ++n)
            yo[n * 16] = accY[n][r] * inv[r];
    }
}

// ---------------------------------------------------------------------------
extern "C" void kernel_launch(void* const* d_in, const int* in_sizes, int n_in,
                              void* d_out, int out_size, void* d_ws, size_t ws_size,
                              hipStream_t stream)
{
    const float* x      = (const float*)d_in[0];
    const float* w_attn = (const float*)d_in[1];
    const float* w_proj = (const float*)d_in[2];
    float* out = (float*)d_out;

    // workspace layout: qkvg (25.3MB) | Lg (128KB) | yb (8.4MB) | Vtb (4MB)
    float* qkvg = (float*)d_ws;
    float* Lg   = qkvg + (size_t)B_ * T_ * QKVG_;
    float* yb   = Lg + (size_t)B_ * H_ * T_;
    unsigned short* Vtb = (unsigned short*)(yb + (size_t)B_ * T_ * H_ * D_);

    const int M = B_ * T_;   // 4096

    // 1) qkvg = x @ w_attn
    gemm_f32<<<dim3((QKVG_ + 63) / 64, M / 128), 256, 0, stream>>>(
        x, w_attn, qkvg, M, QKVG_, C_);

    // 2) RoPE(q,k) + log-sigmoid gate
    prep_kernel<<<(B_ * T_ * H_ * 32) / 256, 256, 0, stream>>>(qkvg, Lg);

    // 3) cumsum over t per (b,h)
    cumsum_kernel<<<B_ * H_, 64, 0, stream>>>(Lg);

    // 3b) pack V^T to bf16 [bh][d][t]
    vt_pack<<<dim3(T_ / 64, B_ * H_), 256, 0, stream>>>(qkvg, Vtb);

    // 4) gated sympow attention (MFMA) -> yb
    attn_mfma<<<dim3(T_ / 64, B_ * H_), 256, 0, stream>>>(qkvg, Lg, Vtb, yb);

    // 5) out = yb @ w_proj
    gemm_f32<<<dim3(C_ / 64, M / 128), 256, 0, stream>>>(
        yb, w_proj, out, M, C_, H_ * D_);
}

// Round 4
// 131.325 us; speedup vs baseline: 6.7930x; 1.9109x over previous
//
#include <hip/hip_runtime.h>
#include <math.h>

// Problem constants (fixed by setup_inputs)
constexpr int B_ = 2, T_ = 2048, C_ = 512, H_ = 8, D_ = 64;
constexpr int QKVG_ = 3 * H_ * D_ + H_;   // 1544
constexpr float GATE_BIAS_ = 6.906768f;
constexpr int NPAD1_ = 1664;              // 13 * 128 (gemm1 padded N)

typedef __attribute__((ext_vector_type(8))) short short8;
typedef __attribute__((ext_vector_type(4))) float f32x4;

__device__ __forceinline__ unsigned short f2b(float f) {
    unsigned int u = __float_as_uint(f);
    unsigned int r = (u + 0x7fffu + ((u >> 16) & 1u)) >> 16;   // RNE
    return (unsigned short)r;
}
__device__ __forceinline__ short8 pack8(float4 a, float4 b) {
    short8 r;
    r[0] = (short)f2b(a.x); r[1] = (short)f2b(a.y);
    r[2] = (short)f2b(a.z); r[3] = (short)f2b(a.w);
    r[4] = (short)f2b(b.x); r[5] = (short)f2b(b.y);
    r[6] = (short)f2b(b.z); r[7] = (short)f2b(b.w);
    return r;
}

// ---------------------------------------------------------------------------
// cvt_bf16: fp32 -> bf16, 8 elements/thread
// ---------------------------------------------------------------------------
__global__ __launch_bounds__(256) void cvt_bf16(
    const float* __restrict__ in, unsigned short* __restrict__ outp, int n8)
{
    const int i = blockIdx.x * 256 + threadIdx.x;
    if (i < n8) {
        float4 f0 = *(const float4*)(in + (size_t)i * 8);
        float4 f1 = *(const float4*)(in + (size_t)i * 8 + 4);
        *(short8*)(outp + (size_t)i * 8) = pack8(f0, f1);
    }
}

// ---------------------------------------------------------------------------
// packT: W[K][N] fp32 row-major -> Bt[Npad][K] bf16 (transposed, zero-padded)
// grid: (Npad/64, K/64), 256 threads
// ---------------------------------------------------------------------------
__global__ __launch_bounds__(256) void packT(
    const float* __restrict__ W, unsigned short* __restrict__ Bt,
    int K, int N)
{
    __shared__ float Ws[64][65];
    const int tid = threadIdx.x;
    const int nt = blockIdx.x * 64;
    const int kt = blockIdx.y * 64;

    {
        const int r = tid >> 2;             // k-row in tile
        const int c0 = (tid & 3) * 16;      // n-col chunk
#pragma unroll
        for (int j = 0; j < 16; ++j) {
            const int n = nt + c0 + j;
            Ws[r][c0 + j] = (n < N) ? W[(size_t)(kt + r) * N + n] : 0.f;
        }
    }
    __syncthreads();
    {
        const int d = tid >> 2;             // n within tile
        const int kc = (tid & 3) * 16;      // k chunk
        short8 o0, o1;
#pragma unroll
        for (int j = 0; j < 8; ++j) o0[j] = (short)f2b(Ws[kc + j][d]);
#pragma unroll
        for (int j = 0; j < 8; ++j) o1[j] = (short)f2b(Ws[kc + 8 + j][d]);
        unsigned short* op = Bt + (size_t)(nt + d) * K + kt + kc;
        *(short8*)(op + 0) = o0;
        *(short8*)(op + 8) = o1;
    }
}

// ---------------------------------------------------------------------------
// gemm_bf16: C[M,N] f32 = A[M,K]bf16 @ Bt[Npad,K]bf16^T
// 128x128 tile, 4 waves (2x2), 4x4 16x16x32 fragments per wave, BK=64
// LDS XOR-swizzled: byte_in_row ^= (row&7)<<4  (rows are 64 bf16 = 128 B)
// ---------------------------------------------------------------------------
__global__ __launch_bounds__(256) void gemm_bf16(
    const unsigned short* __restrict__ A, const unsigned short* __restrict__ Bt,
    float* __restrict__ C, int M, int N, int K)
{
    __shared__ __align__(16) char AsB[128 * 128];   // 16 KB
    __shared__ __align__(16) char BsB[128 * 128];   // 16 KB

    const int tid = threadIdx.x;
    const int wave = tid >> 6, lane = tid & 63;
    const int l15 = lane & 15, lhi = lane >> 4;
    const int wr = wave >> 1, wc = wave & 1;
    const int bm = blockIdx.y * 128, bn = blockIdx.x * 128;

    f32x4 acc[4][4];
#pragma unroll
    for (int i = 0; i < 4; ++i)
#pragma unroll
        for (int j = 0; j < 4; ++j) acc[i][j] = (f32x4){0.f, 0.f, 0.f, 0.f};

    const unsigned short* Arow = A + (size_t)bm * K;
    const unsigned short* Brow = Bt + (size_t)bn * K;
    const int sw = (l15 & 7) << 4;

    for (int k0 = 0; k0 < K; k0 += 64) {
        __syncthreads();
#pragma unroll
        for (int p = 0; p < 4; ++p) {
            const int idx = p * 256 + tid;      // 0..1023
            const int row = idx >> 3;           // 0..127
            const int kc = (idx & 7) * 8;       // bf16 offset in row
            const int ldso = row * 128 + ((kc * 2) ^ ((row & 7) << 4));
            *(short8*)(AsB + ldso) = *(const short8*)(Arow + (size_t)row * K + k0 + kc);
            *(short8*)(BsB + ldso) = *(const short8*)(Brow + (size_t)row * K + k0 + kc);
        }
        __syncthreads();

        short8 af[4][2];
#pragma unroll
        for (int mi = 0; mi < 4; ++mi) {
            const int row = wr * 64 + mi * 16 + l15;
#pragma unroll
            for (int kk = 0; kk < 2; ++kk)
                af[mi][kk] = *(const short8*)(AsB + row * 128 + ((kk * 64 + lhi * 16) ^ sw));
        }
#pragma unroll
        for (int ni = 0; ni < 4; ++ni) {
            const int row = wc * 64 + ni * 16 + l15;
            short8 bf0 = *(const short8*)(BsB + row * 128 + ((lhi * 16) ^ sw));
            short8 bf1 = *(const short8*)(BsB + row * 128 + ((64 + lhi * 16) ^ sw));
#pragma unroll
            for (int mi = 0; mi < 4; ++mi) {
                acc[mi][ni] = __builtin_amdgcn_mfma_f32_16x16x32_bf16(af[mi][0], bf0, acc[mi][ni], 0, 0, 0);
                acc[mi][ni] = __builtin_amdgcn_mfma_f32_16x16x32_bf16(af[mi][1], bf1, acc[mi][ni], 0, 0, 0);
            }
        }
    }

#pragma unroll
    for (int mi = 0; mi < 4; ++mi) {
        const int gm = bm + wr * 64 + mi * 16 + lhi * 4;
#pragma unroll
        for (int r = 0; r < 4; ++r) {
            float* crow = C + (size_t)(gm + r) * N;
#pragma unroll
            for (int ni = 0; ni < 4; ++ni) {
                const int gn = bn + wc * 64 + ni * 16 + l15;
                if (gn < N) crow[gn] = acc[mi][ni][r];
            }
        }
    }
}

// ---------------------------------------------------------------------------
// prep: RoPE q,k in-place + log-sigmoid gate -> Lg
// ---------------------------------------------------------------------------
__global__ __launch_bounds__(256) void prep_kernel(
    float* __restrict__ qkvg, float* __restrict__ Lg)
{
    const int gid = blockIdx.x * 256 + threadIdx.x;
    const int i = gid & 31;
    const int h = (gid >> 5) & 7;
    const int t = (gid >> 8) & 2047;
    const int b = gid >> 19;

    const float div = 6.2831853071795864f * exp2f((float)i * (-11.0f / 32.0f));
    const float ang = (float)t * div;
    const float sn = sinf(ang);
    const float cs = cosf(ang);

    float* qp = qkvg + (size_t)(b * T_ + t) * QKVG_ + h * 64 + 2 * i;
    float x1 = qp[0], x2 = qp[1];
    qp[0] = x1 * cs - x2 * sn;
    qp[1] = x2 * cs + x1 * sn;
    float* kp = qp + 512;
    x1 = kp[0]; x2 = kp[1];
    kp[0] = x1 * cs - x2 * sn;
    kp[1] = x2 * cs + x1 * sn;

    if (i == 0) {
        const float z = qkvg[(size_t)(b * T_ + t) * QKVG_ + 1536 + h] + GATE_BIAS_;
        const float lg = (z > 0.f) ? -log1pf(expf(-z)) : (z - log1pf(expf(z)));
        Lg[(size_t)(b * H_ + h) * T_ + t] = lg;
    }
}

// ---------------------------------------------------------------------------
// cumsum over t per (b,h)
// ---------------------------------------------------------------------------
__global__ __launch_bounds__(64) void cumsum_kernel(float* __restrict__ Lg)
{
    const int bh = blockIdx.x;
    const int lane = threadIdx.x;
    float* p = Lg + (size_t)bh * T_;
    float carry = 0.f;
    for (int c0 = 0; c0 < T_; c0 += 64) {
        float v = p[c0 + lane];
#pragma unroll
        for (int off = 1; off < 64; off <<= 1) {
            float n = __shfl_up(v, off, 64);
            if (lane >= off) v += n;
        }
        v += carry;
        p[c0 + lane] = v;
        carry = __shfl(v, 63, 64);
    }
}

// ---------------------------------------------------------------------------
// vt_pack: V (fp32, strided inside qkvg) -> Vtb[bh][d][t] bf16 (transposed)
// ---------------------------------------------------------------------------
__global__ __launch_bounds__(256) void vt_pack(
    const float* __restrict__ qkvg, unsigned short* __restrict__ Vtb)
{
    __shared__ float Vs[64][68];
    const int tid = threadIdx.x;
    const int stile = blockIdx.x;
    const int bh = blockIdx.y;
    const int b = bh >> 3, h = bh & 7;

    {
        const int r = tid >> 2, c = tid & 3;
        const float* vp = qkvg + (size_t)(b * T_ + stile * 64 + r) * QKVG_ + 1024 + h * 64 + c * 16;
        *(float4*)&Vs[r][c * 16 + 0]  = *(const float4*)(vp + 0);
        *(float4*)&Vs[r][c * 16 + 4]  = *(const float4*)(vp + 4);
        *(float4*)&Vs[r][c * 16 + 8]  = *(const float4*)(vp + 8);
        *(float4*)&Vs[r][c * 16 + 12] = *(const float4*)(vp + 12);
    }
    __syncthreads();
    {
        const int d = tid >> 2, cc = tid & 3;
        short8 o0, o1;
#pragma unroll
        for (int j = 0; j < 8; ++j) o0[j] = (short)f2b(Vs[cc * 16 + j][d]);
#pragma unroll
        for (int j = 0; j < 8; ++j) o1[j] = (short)f2b(Vs[cc * 16 + 8 + j][d]);
        unsigned short* op = Vtb + (size_t)(bh * 64 + d) * T_ + stile * 64 + cc * 16;
        *(short8*)(op + 0) = o0;
        *(short8*)(op + 8) = o1;
    }
}

// ---------------------------------------------------------------------------
// attn_mfma: 4 waves/block, wave w owns q-rows [t0+16w, t0+16w+16)
// per 64-wide KV tile: QK^T (8 mfma) -> gate/square -> P to LDS (bf16,
// XOR-swizzled) -> PV (8 mfma). den = plain row-sum (scores >= 0).
// Output y written as bf16 (feeds gemm_bf16 #2 directly).
// ---------------------------------------------------------------------------
__global__ __launch_bounds__(256) void attn_mfma(
    const float* __restrict__ qkvg, const float* __restrict__ L,
    const unsigned short* __restrict__ Vtb, unsigned short* __restrict__ ybb)
{
    __shared__ __align__(16) char smem[32768];
    char* KsB = smem;                 // 8 KB  [s][d] bf16 swizzled
    char* VtB = smem + 8192;          // 8 KB  [d][s] bf16 swizzled
    char* PsB = smem + 16384;         // 8 KB  4 waves x [16][64] bf16 swizzled
    float* Lall = (float*)(smem + 24576);  // up to 2048 floats

    const int tid = threadIdx.x;
    const int wave = tid >> 6;
    const int lane = tid & 63;
    const int l15 = lane & 15;
    const int lhi = lane >> 4;        // 0..3
    const int bt = blockIdx.x;
    const int bh = blockIdx.y;
    const int b = bh >> 3, h = bh & 7;
    const int t0 = bt * 64;

    const float* Lrow = L + (size_t)bh * T_;
    for (int i = tid; i < (bt + 1) * 64; i += 256) Lall[i] = Lrow[i];

    // Q fragments (A-frag: row = l15, k = kk*32 + lhi*8 + j)
    const int qrow = t0 + wave * 16 + l15;
    const float* qp = qkvg + (size_t)(b * T_ + qrow) * QKVG_ + h * 64 + lhi * 8;
    short8 qf[2];
#pragma unroll
    for (int kk = 0; kk < 2; ++kk) {
        float4 f0 = *(const float4*)(qp + kk * 32);
        float4 f1 = *(const float4*)(qp + kk * 32 + 4);
        qf[kk] = pack8(f0, f1);
    }

    __syncthreads();   // Lall visible

    float eLt[4];
#pragma unroll
    for (int r = 0; r < 4; ++r)
        eLt[r] = __expf(Lall[t0 + wave * 16 + lhi * 4 + r]) * (1.0f / 64.0f);

    f32x4 accY[4];
#pragma unroll
    for (int n = 0; n < 4; ++n) accY[n] = (f32x4){0.f, 0.f, 0.f, 0.f};
    float den[4] = {0.f, 0.f, 0.f, 0.f};

    const int kchunk = lhi * 16;

    for (int st = 0; st <= bt; ++st) {
        __syncthreads();
        {
            const int s = tid >> 2, cq = tid & 3;
            const float* kp = qkvg + (size_t)(b * T_ + st * 64 + s) * QKVG_ + 512 + h * 64 + cq * 16;
            float4 k0 = *(const float4*)(kp + 0);
            float4 k1 = *(const float4*)(kp + 4);
            float4 k2 = *(const float4*)(kp + 8);
            float4 k3 = *(const float4*)(kp + 12);
            const int sw = (s & 7) << 4;
            *(short8*)(KsB + s * 128 + ((cq * 32) ^ sw))      = pack8(k0, k1);
            *(short8*)(KsB + s * 128 + ((cq * 32 + 16) ^ sw)) = pack8(k2, k3);
            const int d = s;
            const unsigned short* vp = Vtb + (size_t)(bh * 64 + d) * T_ + st * 64 + cq * 16;
            short8 v0 = *(const short8*)(vp + 0);
            short8 v1 = *(const short8*)(vp + 8);
            *(short8*)(VtB + d * 128 + ((cq * 32) ^ sw))      = v0;
            *(short8*)(VtB + d * 128 + ((cq * 32 + 16) ^ sw)) = v1;
        }
        __syncthreads();

        f32x4 accS[4];
#pragma unroll
        for (int n = 0; n < 4; ++n) accS[n] = (f32x4){0.f, 0.f, 0.f, 0.f};
        const int rsw = (l15 & 7) << 4;
#pragma unroll
        for (int n = 0; n < 4; ++n) {
#pragma unroll
            for (int kk = 0; kk < 2; ++kk) {
                short8 bf = *(const short8*)(KsB + (n * 16 + l15) * 128 + ((kk * 64 + kchunk) ^ rsw));
                accS[n] = __builtin_amdgcn_mfma_f32_16x16x32_bf16(qf[kk], bf, accS[n], 0, 0, 0);
            }
        }

        float eLsi[4];
#pragma unroll
        for (int n = 0; n < 4; ++n)
            eLsi[n] = __expf(-Lall[st * 64 + n * 16 + l15]);
        const bool last = (st == bt);
        char* PsW = PsB + wave * 2048;
#pragma unroll
        for (int n = 0; n < 4; ++n) {
#pragma unroll
            for (int r = 0; r < 4; ++r) {
                const float a = accS[n][r];
                float p = a * a * eLt[r] * eLsi[n];
                if (last) {
                    const int scol = n * 16 + l15;
                    const int trow = lhi * 4 + r;
                    p = (scol <= wave * 16 + trow) ? p : 0.f;
                }
                den[r] += p;
                const int prow = lhi * 4 + r;
                const int pcol = n * 16 + l15;
                *(unsigned short*)(PsW + prow * 128 + ((2 * pcol) ^ ((prow & 7) << 4))) = f2b(p);
            }
        }

        short8 pa[2];
#pragma unroll
        for (int kk = 0; kk < 2; ++kk)
            pa[kk] = *(const short8*)(PsW + l15 * 128 + ((kk * 64 + kchunk) ^ rsw));
#pragma unroll
        for (int n = 0; n < 4; ++n) {
#pragma unroll
            for (int kk = 0; kk < 2; ++kk) {
                short8 vb = *(const short8*)(VtB + (n * 16 + l15) * 128 + ((kk * 64 + kchunk) ^ rsw));
                accY[n] = __builtin_amdgcn_mfma_f32_16x16x32_bf16(pa[kk], vb, accY[n], 0, 0, 0);
            }
        }
    }

#pragma unroll
    for (int r = 0; r < 4; ++r) {
        den[r] += __shfl_xor(den[r], 1, 64);
        den[r] += __shfl_xor(den[r], 2, 64);
        den[r] += __shfl_xor(den[r], 4, 64);
        den[r] += __shfl_xor(den[r], 8, 64);
    }
    float inv[4];
#pragma unroll
    for (int r = 0; r < 4; ++r) inv[r] = 1.0f / fmaxf(den[r], 1e-6f);

    // store Y as bf16: row = t0+16w+lhi*4+r, col = h*64 + n*16 + l15
#pragma unroll
    for (int r = 0; r < 4; ++r) {
        const int t = t0 + wave * 16 + lhi * 4 + r;
        unsigned short* yo = ybb + (size_t)(b * T_ + t) * (H_ * D_) + h * 64 + l15;
#pragma unroll
        for (int n = 0; n < 4; ++n)
            yo[n * 16] = f2b(accY[n][r] * inv[r]);
    }
}

// ---------------------------------------------------------------------------
extern "C" void kernel_launch(void* const* d_in, const int* in_sizes, int n_in,
                              void* d_out, int out_size, void* d_ws, size_t ws_size,
                              hipStream_t stream)
{
    const float* x      = (const float*)d_in[0];
    const float* w_attn = (const float*)d_in[1];
    const float* w_proj = (const float*)d_in[2];
    float* out = (float*)d_out;

    // workspace layout (36.0 MB):
    // qkvg f32 | Lg f32 | Vtb bf16 | Bt1 bf16 | Bt2 bf16 | xb/ybb bf16 (union)
    float* qkvg = (float*)d_ws;
    float* Lg = qkvg + (size_t)B_ * T_ * QKVG_;              // 6,322,176 f
    unsigned short* Vtb = (unsigned short*)(Lg + (size_t)B_ * H_ * T_);
    unsigned short* Bt1 = Vtb + (size_t)B_ * H_ * D_ * T_;   // +2,097,152
    unsigned short* Bt2 = Bt1 + (size_t)NPAD1_ * C_;         // +851,968
    unsigned short* xb  = Bt2 + (size_t)C_ * C_;             // +262,144
    unsigned short* ybb = xb;  // union: xb dead after gemm1, ybb written by attn

    const int M = B_ * T_;   // 4096

    // 0) packs: x -> bf16; w_attn -> Bt1[1664][512]; w_proj -> Bt2[512][512]
    cvt_bf16<<<(M * C_ / 8 + 255) / 256, 256, 0, stream>>>(x, xb, M * C_ / 8);
    packT<<<dim3(NPAD1_ / 64, C_ / 64), 256, 0, stream>>>(w_attn, Bt1, C_, QKVG_);
    packT<<<dim3(C_ / 64, (H_ * D_) / 64), 256, 0, stream>>>(w_proj, Bt2, H_ * D_, C_);

    // 1) qkvg = x @ w_attn   (MFMA bf16)
    gemm_bf16<<<dim3(NPAD1_ / 128, M / 128), 256, 0, stream>>>(
        xb, Bt1, qkvg, M, QKVG_, C_);

    // 2) RoPE(q,k) + log-sigmoid gate
    prep_kernel<<<(B_ * T_ * H_ * 32) / 256, 256, 0, stream>>>(qkvg, Lg);

    // 3) cumsum over t per (b,h)
    cumsum_kernel<<<B_ * H_, 64, 0, stream>>>(Lg);

    // 3b) pack V^T to bf16 [bh][d][t]
    vt_pack<<<dim3(T_ / 64, B_ * H_), 256, 0, stream>>>(qkvg, Vtb);

    // 4) gated sympow attention (MFMA) -> ybb (bf16)
    attn_mfma<<<dim3(T_ / 64, B_ * H_), 256, 0, stream>>>(qkvg, Lg, Vtb, ybb);

    // 5) out = ybb @ w_proj  (MFMA bf16)
    gemm_bf16<<<dim3((C_) / 128, M / 128), 256, 0, stream>>>(
        ybb, Bt2, out, M, C_, H_ * D_);
}